// Round 10
// baseline (276.616 us; speedup 1.0000x reference)
//
#include <hip/hip_runtime.h>
#include <math.h>

#define NT 4
#define BSZ 4
#define BB 16
#define NS 1024
#define MAXL 3

typedef unsigned short u16;
typedef __attribute__((ext_vector_type(8))) short bf16x8;
typedef __attribute__((ext_vector_type(4))) float f32x4;

struct LayerP {
    const float *g, *t;
    const int *ix, *iy;
    u16 *Xt, *Yt, *Xs, *Ys;          // c-major gathers; s-major transposes
    float *xp, *yp;                  // per-(C/64)-tile per-sample sumsq partials
    float *xcs, *ycs;                // per-(ctile,stile) channel-sum partials [nb][C/64][16][64]
    float *rxn, *ryn;                // reciprocal sample norms
    float *sx, *sy;                  // per-channel sums
    unsigned *m1u, *m2u;
    float *cov;
    int C, n, nchunk, ntri, lid, xblk, yblk;
};
struct Tab {
    LayerP L[MAXL];
    int nl, nb, b0;
    float* losspart;   // [BB][3]
};

__device__ __forceinline__ unsigned fenc(float f) {
    unsigned u = __float_as_uint(f);
    return (u & 0x80000000u) ? ~u : (u | 0x80000000u);
}
__device__ __forceinline__ float fdec(unsigned u) {
    unsigned v = (u & 0x80000000u) ? (u & 0x7FFFFFFFu) : ~u;
    return __uint_as_float(v);
}
__device__ __forceinline__ u16 f2bf(float f) {  // RNE
    unsigned u = __float_as_uint(f);
    unsigned r = u + 0x7FFFu + ((u >> 16) & 1u);
    return (u16)(r >> 16);
}
__device__ __forceinline__ float bf2f(u16 h) {
    return __uint_as_float((unsigned)h << 16);
}

// Direct random gather with deep MLP: thread = one sample, 64 independent
// channel loads issued before any store (v[64] static-indexed -> registers).
// Writes coalesced (fixed channel, contiguous samples across the wave).
__global__ __launch_bounds__(256) void gather(Tab tab)
{
    int f = blockIdx.x;
    int l = 0, side = 0;
    #pragma unroll
    for (int li = 0; li < MAXL; ++li) {
        if (li >= tab.nl) break;
        if (f < tab.L[li].xblk) { l = li; side = 0; goto decoded; }
        f -= tab.L[li].xblk;
        if (f < tab.L[li].yblk) { l = li; side = 1; goto decoded; }
        f -= tab.L[li].yblk;
    }
decoded:;
    const LayerP P = tab.L[l];
    int ng = P.C >> 6;
    int cgi = f % ng; f /= ng;
    int sq = f & 3; f >>= 2;
    int bl = f;
    int bg = tab.b0 + bl;
    int c0 = cgi * 64;
    int tid = threadIdx.x;
    int s = sq * 256 + tid;
    int n = P.n;
    int idx = side ? P.iy[bg * NS + s] : P.ix[bg * NS + s];
    const float* __restrict__ src =
        (side ? P.t + ((size_t)(bg % NT) * P.C + c0) * n
              : P.g + ((size_t)bg * P.C + c0) * n) + idx;
    u16* __restrict__ dst = (side ? P.Yt : P.Xt) + ((size_t)bl * P.C + c0) * NS + s;
    float v[64];
    #pragma unroll
    for (int j = 0; j < 64; ++j) v[j] = src[(size_t)j * n];
    #pragma unroll
    for (int j = 0; j < 64; ++j) dst[(size_t)j * NS] = f2bf(v[j]);
}

// 64x64 plain transpose (c-major -> s-major) + fused per-sample sumsq partials
// + fused per-channel sum partials (over this block's 64-sample stile).
__global__ void transpose_k(Tab tab)
{
    int x = blockIdx.x, l = 0;
    while (l < MAXL - 1 && x >= tab.L[l].C / 64) { x -= tab.L[l].C / 64; ++l; }
    const LayerP P = tab.L[l];
    int z = blockIdx.z;
    int bl = z >> 1, which = z & 1;
    const u16* __restrict__ Zt = which ? P.Yt : P.Xt;
    u16* __restrict__ Zs = which ? P.Ys : P.Xs;
    float* __restrict__ zp = which ? P.yp : P.xp;
    float* __restrict__ zcs = which ? P.ycs : P.xcs;
    int C = P.C;
    int ctile = x;
    int c0 = ctile * 64, s0 = blockIdx.y * 64;
    int stile = blockIdx.y;
    __shared__ __align__(16) u16 T[64][72];
    int tid = threadIdx.x;
    #pragma unroll
    for (int rep = 0; rep < 2; ++rep) {
        int q = tid + rep * 256;
        int rr = q >> 3, seg = q & 7;
        float4 f4 = *(const float4*)&Zt[((size_t)bl * C + c0 + rr) * NS + s0 + seg * 8];
        *(float4*)&T[rr][seg * 8] = f4;
        const u16* hp = (const u16*)&f4;
        float p = 0.f;
        #pragma unroll
        for (int e = 0; e < 8; ++e) p += bf2f(hp[e]);
        p += __shfl_xor(p, 1);
        p += __shfl_xor(p, 2);
        p += __shfl_xor(p, 4);
        if (seg == 0)
            zcs[(((size_t)bl * P.nchunk + ctile) * 16 + stile) * 64 + rr] = p;
    }
    __syncthreads();
    #pragma unroll
    for (int rep = 0; rep < 2; ++rep) {
        int q = tid + rep * 256;
        int sr = q >> 3, cs = q & 7;
        __align__(16) u16 tmp[8];
        float p = 0.f;
        #pragma unroll
        for (int e = 0; e < 8; ++e) {
            u16 h = T[cs * 8 + e][sr];
            tmp[e] = h;
            float v = bf2f(h);
            p = fmaf(v, v, p);
        }
        *(float4*)&Zs[((size_t)bl * NS + s0 + sr) * C + c0 + cs * 8] = *(float4*)tmp;
        p += __shfl_xor(p, 1);
        p += __shfl_xor(p, 2);
        p += __shfl_xor(p, 4);
        if (cs == 0)
            zp[((size_t)bl * P.nchunk + ctile) * NS + s0 + sr] = p;
    }
}

// Reduce sumsq partials -> reciprocal norms; init min buffers; reduce channel-sum
// stile partials -> sx/sy.
__global__ void colnorm_reduce(Tab tab)
{
    const LayerP P = tab.L[blockIdx.y];
    int bl = blockIdx.z;
    int s = blockIdx.x * 256 + threadIdx.x;
    float ax = 0.f, ay = 0.f;
    for (int k = 0; k < P.nchunk; ++k) {
        size_t o = ((size_t)bl * P.nchunk + k) * NS + s;
        ax += P.xp[o];
        ay += P.yp[o];
    }
    P.rxn[bl * NS + s] = rsqrtf(ax);
    P.ryn[bl * NS + s] = rsqrtf(ay);
    P.m1u[bl * NS + s] = 0xFFFFFFFFu;
    P.m2u[bl * NS + s] = 0xFFFFFFFFu;
    int cq = P.C >> 2;
    for (int c = blockIdx.x * cq + threadIdx.x; c < (blockIdx.x + 1) * cq; c += 256) {
        int ct = c >> 6, cr = c & 63;
        float sx = 0.f, sy = 0.f;
        for (int st = 0; st < 16; ++st) {
            size_t o = (((size_t)bl * P.nchunk + ct) * 16 + st) * 64 + cr;
            sx += P.xcs[o];
            sy += P.ycs[o];
        }
        P.sx[bl * P.C + c] = sx;
        P.sy[bl * P.C + c] = sy;
    }
}

// 128x128 MFMA tile of cos-dist = 1 - (X.Y^T)*rx_i*ry_j; fused row/col min epilogue.
__global__ __launch_bounds__(256) void cross_mfma(Tab tab)
{
    int z = blockIdx.z;
    int l = z / tab.nb, bl = z - l * tab.nb;
    const LayerP P = tab.L[l];
    int C = P.C;
    int i0 = blockIdx.x * 128, j0 = blockIdx.y * 128;
    __shared__ __align__(16) u16 As[128][40], Bs[128][40];
    int tid = threadIdx.x;
    int w = tid >> 6, lane = tid & 63;
    int wr = w >> 1, wc = w & 1;
    int q = lane >> 4, r = lane & 15;
    const u16* __restrict__ Xb = P.Xs + ((size_t)bl * NS + i0) * C;
    const u16* __restrict__ Yb = P.Ys + ((size_t)bl * NS + j0) * C;
    f32x4 acc[4][4];
    #pragma unroll
    for (int m = 0; m < 4; ++m)
        #pragma unroll
        for (int nn = 0; nn < 4; ++nn) acc[m][nn] = (f32x4){0.f, 0.f, 0.f, 0.f};

    for (int kk = 0; kk < C; kk += 32) {
        __syncthreads();
        #pragma unroll
        for (int rep = 0; rep < 2; ++rep) {
            int qid = tid + rep * 256;
            int row = qid >> 2, seg = qid & 3;
            size_t off = (size_t)row * C + kk + seg * 8;
            *(float4*)&As[row][seg * 8] = *(const float4*)&Xb[off];
            *(float4*)&Bs[row][seg * 8] = *(const float4*)&Yb[off];
        }
        __syncthreads();
        bf16x8 a[4], b[4];
        #pragma unroll
        for (int m = 0; m < 4; ++m)
            a[m] = *(const bf16x8*)&As[wr * 64 + m * 16 + r][q * 8];
        #pragma unroll
        for (int nn = 0; nn < 4; ++nn)
            b[nn] = *(const bf16x8*)&Bs[wc * 64 + nn * 16 + r][q * 8];
        #pragma unroll
        for (int m = 0; m < 4; ++m)
            #pragma unroll
            for (int nn = 0; nn < 4; ++nn)
                acc[m][nn] = __builtin_amdgcn_mfma_f32_16x16x32_bf16(a[m], b[nn], acc[m][nn], 0, 0, 0);
    }

    float rxl[4][4], ryl[4];
    #pragma unroll
    for (int m = 0; m < 4; ++m)
        #pragma unroll
        for (int reg = 0; reg < 4; ++reg)
            rxl[m][reg] = P.rxn[bl * NS + i0 + wr * 64 + m * 16 + q * 4 + reg];
    #pragma unroll
    for (int nn = 0; nn < 4; ++nn)
        ryl[nn] = P.ryn[bl * NS + j0 + wc * 64 + nn * 16 + r];

    float rm[4][4], cm[4];
    #pragma unroll
    for (int m = 0; m < 4; ++m)
        #pragma unroll
        for (int reg = 0; reg < 4; ++reg) rm[m][reg] = 1e30f;
    #pragma unroll
    for (int nn = 0; nn < 4; ++nn) cm[nn] = 1e30f;
    #pragma unroll
    for (int m = 0; m < 4; ++m)
        #pragma unroll
        for (int nn = 0; nn < 4; ++nn)
            #pragma unroll
            for (int reg = 0; reg < 4; ++reg) {
                float d = 1.f - acc[m][nn][reg] * rxl[m][reg] * ryl[nn];
                rm[m][reg] = fminf(rm[m][reg], d);
                cm[nn] = fminf(cm[nn], d);
            }
    #pragma unroll
    for (int m = 0; m < 4; ++m)
        #pragma unroll
        for (int reg = 0; reg < 4; ++reg) {
            float v = rm[m][reg];
            v = fminf(v, __shfl_xor(v, 1));
            v = fminf(v, __shfl_xor(v, 2));
            v = fminf(v, __shfl_xor(v, 4));
            v = fminf(v, __shfl_xor(v, 8));
            rm[m][reg] = v;
        }
    if (r == 0) {
        #pragma unroll
        for (int m = 0; m < 4; ++m)
            #pragma unroll
            for (int reg = 0; reg < 4; ++reg) {
                int i = i0 + wr * 64 + m * 16 + q * 4 + reg;
                atomicMin(&P.m2u[bl * NS + i], fenc(rm[m][reg]));
            }
    }
    #pragma unroll
    for (int nn = 0; nn < 4; ++nn) {
        float v = cm[nn];
        v = fminf(v, __shfl_xor(v, 16));
        v = fminf(v, __shfl_xor(v, 32));
        cm[nn] = v;
    }
    if (q == 0) {
        #pragma unroll
        for (int nn = 0; nn < 4; ++nn) {
            int j = j0 + wc * 64 + nn * 16 + r;
            atomicMin(&P.m1u[bl * NS + j], fenc(cm[nn]));
        }
    }
}

// Dual 128x128 MFMA tile of Sxx/Syy; upper-triangle tiles, off-diag weighted 2x.
__global__ __launch_bounds__(256) void cov_mfma(Tab tab)
{
    int x = blockIdx.x, l = 0;
    while (l < MAXL - 1 && x >= tab.L[l].ntri) { x -= tab.L[l].ntri; ++l; }
    const LayerP P = tab.L[l];
    int u = x;
    int bl = blockIdx.y;
    int C = P.C;
    int ty = 0;
    while ((ty + 1) * (ty + 2) / 2 <= u) ++ty;
    int tx = u - ty * (ty + 1) / 2;
    int c0 = ty * 128, d0 = tx * 128;
    float wgt = (tx == ty) ? 1.f : 2.f;

    __shared__ __align__(16) u16 As[128][40], Bs[128][40], Cs2[128][40], Ds[128][40];
    int tid = threadIdx.x;
    int w = tid >> 6, lane = tid & 63;
    int wr = w >> 1, wc = w & 1;
    int q = lane >> 4, r = lane & 15;
    const u16* __restrict__ Xc = P.Xt + ((size_t)bl * C + c0) * NS;
    const u16* __restrict__ Xd = P.Xt + ((size_t)bl * C + d0) * NS;
    const u16* __restrict__ Yc = P.Yt + ((size_t)bl * C + c0) * NS;
    const u16* __restrict__ Yd = P.Yt + ((size_t)bl * C + d0) * NS;

    f32x4 accX[4][4], accY[4][4];
    #pragma unroll
    for (int m = 0; m < 4; ++m)
        #pragma unroll
        for (int nn = 0; nn < 4; ++nn) {
            accX[m][nn] = (f32x4){0.f, 0.f, 0.f, 0.f};
            accY[m][nn] = (f32x4){0.f, 0.f, 0.f, 0.f};
        }

    for (int ss = 0; ss < NS; ss += 32) {
        __syncthreads();
        #pragma unroll
        for (int rep = 0; rep < 2; ++rep) {
            int qid = tid + rep * 256;
            int row = qid >> 2, seg = qid & 3;
            size_t off = (size_t)row * NS + ss + seg * 8;
            *(float4*)&As[row][seg * 8]  = *(const float4*)&Xc[off];
            *(float4*)&Bs[row][seg * 8]  = *(const float4*)&Xd[off];
            *(float4*)&Cs2[row][seg * 8] = *(const float4*)&Yc[off];
            *(float4*)&Ds[row][seg * 8]  = *(const float4*)&Yd[off];
        }
        __syncthreads();
        {
            bf16x8 a[4], b[4];
            #pragma unroll
            for (int m = 0; m < 4; ++m) a[m] = *(const bf16x8*)&As[wr * 64 + m * 16 + r][q * 8];
            #pragma unroll
            for (int nn = 0; nn < 4; ++nn) b[nn] = *(const bf16x8*)&Bs[wc * 64 + nn * 16 + r][q * 8];
            #pragma unroll
            for (int m = 0; m < 4; ++m)
                #pragma unroll
                for (int nn = 0; nn < 4; ++nn)
                    accX[m][nn] = __builtin_amdgcn_mfma_f32_16x16x32_bf16(a[m], b[nn], accX[m][nn], 0, 0, 0);
        }
        {
            bf16x8 a[4], b[4];
            #pragma unroll
            for (int m = 0; m < 4; ++m) a[m] = *(const bf16x8*)&Cs2[wr * 64 + m * 16 + r][q * 8];
            #pragma unroll
            for (int nn = 0; nn < 4; ++nn) b[nn] = *(const bf16x8*)&Ds[wc * 64 + nn * 16 + r][q * 8];
            #pragma unroll
            for (int m = 0; m < 4; ++m)
                #pragma unroll
                for (int nn = 0; nn < 4; ++nn)
                    accY[m][nn] = __builtin_amdgcn_mfma_f32_16x16x32_bf16(a[m], b[nn], accY[m][nn], 0, 0, 0);
        }
    }

    float scxv[4][4], scyv[4][4], sdxv[4], sdyv[4];
    #pragma unroll
    for (int m = 0; m < 4; ++m)
        #pragma unroll
        for (int reg = 0; reg < 4; ++reg) {
            int c = c0 + wr * 64 + m * 16 + q * 4 + reg;
            scxv[m][reg] = P.sx[bl * C + c];
            scyv[m][reg] = P.sy[bl * C + c];
        }
    #pragma unroll
    for (int nn = 0; nn < 4; ++nn) {
        int d = d0 + wc * 64 + nn * 16 + r;
        sdxv[nn] = P.sx[bl * C + d];
        sdyv[nn] = P.sy[bl * C + d];
    }
    const float invNS = 1.f / NS, invNSm1 = 1.f / (NS - 1);
    float tsum = 0.f;
    #pragma unroll
    for (int m = 0; m < 4; ++m)
        #pragma unroll
        for (int nn = 0; nn < 4; ++nn)
            #pragma unroll
            for (int reg = 0; reg < 4; ++reg) {
                float cx = (accX[m][nn][reg] - scxv[m][reg] * sdxv[nn] * invNS) * invNSm1;
                float cy = (accY[m][nn][reg] - scyv[m][reg] * sdyv[nn] * invNS) * invNSm1;
                tsum += fabsf(cx - cy);
            }
    tsum *= wgt;
    __shared__ float redc[4];
    for (int o = 32; o > 0; o >>= 1) tsum += __shfl_down(tsum, o);
    if (lane == 0) redc[w] = tsum;
    __syncthreads();
    if (tid == 0)
        P.cov[(size_t)bl * P.ntri + u] = redc[0] + redc[1] + redc[2] + redc[3];
}

__global__ void finalize_kernel(Tab tab)
{
    const LayerP P = tab.L[blockIdx.x];
    int bl = blockIdx.y;
    int tid = threadIdx.x;
    int C = P.C;
    float s1 = 0.f, s2 = 0.f, smu = 0.f, scov = 0.f;
    for (int s = tid; s < NS; s += 256) {
        s1 += fdec(P.m1u[bl * NS + s]);
        s2 += fdec(P.m2u[bl * NS + s]);
    }
    for (int c = tid; c < C; c += 256) smu += fabsf(P.sx[bl * C + c] - P.sy[bl * C + c]);
    for (int i = tid; i < P.ntri; i += 256) scov += P.cov[(size_t)bl * P.ntri + i];
    __shared__ float red[4][4];
    for (int o = 32; o > 0; o >>= 1) {
        s1 += __shfl_down(s1, o);
        s2 += __shfl_down(s2, o);
        smu += __shfl_down(smu, o);
        scov += __shfl_down(scov, o);
    }
    int wid = tid >> 6, lane = tid & 63;
    if (lane == 0) { red[0][wid] = s1; red[1][wid] = s2; red[2][wid] = smu; red[3][wid] = scov; }
    __syncthreads();
    if (tid == 0) {
        s1 = red[0][0] + red[0][1] + red[0][2] + red[0][3];
        s2 = red[1][0] + red[1][1] + red[1][2] + red[1][3];
        smu = red[2][0] + red[2][1] + red[2][2] + red[2][3];
        scov = red[3][0] + red[3][1] + red[3][2] + red[3][3];
        float m1m = s1 * (1.f / NS), m2m = s2 * (1.f / NS);
        float mu_diff = smu * (1.f / NS) * (1.f / (float)C);
        float cov_diff = scov / ((float)C * (float)C);
        tab.losspart[(tab.b0 + bl) * 3 + P.lid] = fmaxf(m1m, m2m) + mu_diff + cov_diff;
    }
}

__global__ void out_kernel(const float* __restrict__ lp, float* __restrict__ out)
{
    int t = threadIdx.x;
    if (t < NT) {
        float s = 0.f;
        for (int k = 0; k < BSZ; ++k)
            for (int l = 0; l < 3; ++l)
                s += lp[(k * NT + t) * 3 + l];
        out[t] = s * (1.f / BSZ);
    }
}

static inline size_t alignup(size_t v) { return (v + 255) & ~(size_t)255; }

static size_t layer_bytes(int C, int n, int nb) {
    int nchunk = C / 64;
    int tc = C / 128, ntri = tc * (tc + 1) / 2;
    size_t szZ = alignup((size_t)NS * C * 2);
    size_t szP = alignup((size_t)nchunk * NS * 4);
    size_t szCS = alignup((size_t)nb * nchunk * 16 * 64 * 4);
    return (size_t)nb * (4 * szZ + 2 * szP + 4 * alignup(NS * 4)
                         + 2 * alignup(C * 4) + alignup(ntri * 4))
           + 2 * szCS;
}

static char* fill_layer(LayerP& P, char* p, int C, int n, int nb, int lid,
                        const float* g, const float* t, const int* ix, const int* iy) {
    P.g = g; P.t = t; P.ix = ix; P.iy = iy;
    P.C = C; P.n = n; P.lid = lid;
    P.nchunk = C / 64;
    int tc = C / 128;
    P.ntri = tc * (tc + 1) / 2;
    P.xblk = (C / 64) * 4 * nb;
    P.yblk = (C / 64) * 4 * nb;
    size_t szZ = alignup((size_t)NS * C * 2);
    size_t szP = alignup((size_t)P.nchunk * NS * 4);
    size_t szCS = alignup((size_t)nb * P.nchunk * 16 * 64 * 4);
    P.Xt = (u16*)p;  p += nb * szZ;
    P.Yt = (u16*)p;  p += nb * szZ;
    P.Xs = (u16*)p;  p += nb * szZ;
    P.Ys = (u16*)p;  p += nb * szZ;
    P.xp = (float*)p; p += nb * szP;
    P.yp = (float*)p; p += nb * szP;
    P.xcs = (float*)p; p += szCS;
    P.ycs = (float*)p; p += szCS;
    P.rxn = (float*)p; p += nb * alignup(NS * 4);
    P.ryn = (float*)p; p += nb * alignup(NS * 4);
    P.m1u = (unsigned*)p; p += nb * alignup(NS * 4);
    P.m2u = (unsigned*)p; p += nb * alignup(NS * 4);
    P.sx = (float*)p; p += nb * alignup(C * 4);
    P.sy = (float*)p; p += nb * alignup(C * 4);
    P.cov = (float*)p; p += nb * alignup(P.ntri * 4);
    return p;
}

static void launch_group(const Tab& tab, hipStream_t stream) {
    int sumC64 = 0, sumNtri = 0, flatN = 0;
    for (int l = 0; l < tab.nl; ++l) {
        sumC64 += tab.L[l].C / 64;
        sumNtri += tab.L[l].ntri;
        flatN += tab.L[l].xblk + tab.L[l].yblk;
    }
    int nb = tab.nb;
    gather<<<flatN, 256, 0, stream>>>(tab);
    transpose_k<<<dim3(sumC64, NS / 64, nb * 2), 256, 0, stream>>>(tab);
    colnorm_reduce<<<dim3(NS / 256, tab.nl, nb), 256, 0, stream>>>(tab);
    cross_mfma<<<dim3(NS / 128, NS / 128, tab.nl * nb), 256, 0, stream>>>(tab);
    cov_mfma<<<dim3(sumNtri, nb), 256, 0, stream>>>(tab);
    finalize_kernel<<<dim3(tab.nl, nb), 256, 0, stream>>>(tab);
}

extern "C" void kernel_launch(void* const* d_in, const int* in_sizes, int n_in,
                              void* d_out, int out_size, void* d_ws, size_t ws_size,
                              hipStream_t stream)
{
    const float* tp[3] = {(const float*)d_in[0], (const float*)d_in[4], (const float*)d_in[8]};
    const float* gp[3] = {(const float*)d_in[1], (const float*)d_in[5], (const float*)d_in[9]};
    const int* ixp[3]  = {(const int*)d_in[2], (const int*)d_in[6], (const int*)d_in[10]};
    const int* iyp[3]  = {(const int*)d_in[3], (const int*)d_in[7], (const int*)d_in[11]};
    const int Cs[3] = {128, 256, 512};
    const int Sp[3] = {128, 64, 32};

    float* out = (float*)d_out;
    char* ws = (char*)d_ws;
    float* losspart = (float*)ws;           // BB*3 floats
    size_t base = alignup(BB * 3 * 4);
    size_t avail = (ws_size > base) ? ws_size - base : 0;

    size_t need_all = 0;
    for (int l = 0; l < 3; ++l) need_all += layer_bytes(Cs[l], Sp[l] * Sp[l], BB);

    if (avail >= need_all) {
        Tab tab;
        tab.nl = 3; tab.nb = BB; tab.b0 = 0; tab.losspart = losspart;
        char* p = ws + base;
        for (int l = 0; l < 3; ++l)
            p = fill_layer(tab.L[l], p, Cs[l], Sp[l] * Sp[l], BB, l,
                           gp[l], tp[l], ixp[l], iyp[l]);
        launch_group(tab, stream);
    } else {
        for (int l = 0; l < 3; ++l) {
            size_t per_b = layer_bytes(Cs[l], Sp[l] * Sp[l], 1);
            int G = (int)(avail / per_b);
            if (G > BB) G = BB;
            if (G < 1) G = 1;
            for (int b0 = 0; b0 < BB; b0 += G) {
                int nb = (BB - b0 < G) ? (BB - b0) : G;
                Tab tab;
                tab.nl = 1; tab.nb = nb; tab.b0 = b0; tab.losspart = losspart;
                fill_layer(tab.L[0], ws + base, Cs[l], Sp[l] * Sp[l], nb, l,
                           gp[l], tp[l], ixp[l], iyp[l]);
                launch_group(tab, stream);
            }
        }
    }
    out_kernel<<<1, 64, 0, stream>>>(losspart, out);
}

// Round 11
// 225.723 us; speedup vs baseline: 1.2255x; 1.2255x over previous
//
#include <hip/hip_runtime.h>
#include <math.h>

#define NT 4
#define BSZ 4
#define BB 16
#define NS 1024
#define CHF 1024   // floats per LDS chunk (4 KB); 4 slots = 16 KB
#define MAXL 3

typedef unsigned short u16;
typedef __attribute__((ext_vector_type(8))) short bf16x8;
typedef __attribute__((ext_vector_type(4))) float f32x4;

struct LayerP {
    const float *g, *t;
    const int *ix, *iy;
    u16 *Xt, *Yt, *Xs, *Ys;          // c-major gathers; s-major transposes
    float *xp, *yp;                  // per-(C/64)-tile partial sum-of-squares (per sample)
    float *psx, *psy;                // per-slice channel-sum partials [hs][nb][C]
    float *rxn, *ryn;                // reciprocal sample norms
    float *sx, *sy;                  // per-channel sums
    unsigned *m1u, *m2u;
    float *cov;
    int C, n, nchunk, ntri, lid, hs, csl, xblk, yblk;
};
struct Tab {
    LayerP L[MAXL];
    int nl, nb, b0, ysh;
    float* losspart;   // [BB][3]
};

__device__ __forceinline__ unsigned fenc(float f) {
    unsigned u = __float_as_uint(f);
    return (u & 0x80000000u) ? ~u : (u | 0x80000000u);
}
__device__ __forceinline__ float fdec(unsigned u) {
    unsigned v = (u & 0x80000000u) ? (u & 0x7FFFFFFFu) : ~u;
    return __uint_as_float(v);
}
__device__ __forceinline__ u16 f2bf(float f) {  // RNE
    unsigned u = __float_as_uint(f);
    unsigned r = u + 0x7FFFu + ((u >> 16) & 1u);
    return (u16)(r >> 16);
}
__device__ __forceinline__ float bf2f(u16 h) {
    return __uint_as_float((unsigned)h << 16);
}

// Async global->LDS, 16B/lane; LDS dest wave-uniform (+lane*16), source per-lane.
__device__ __forceinline__ void gload16(const void* src, void* dst) {
    __builtin_amdgcn_global_load_lds(
        (const __attribute__((address_space(1))) float*)src,
        (__attribute__((address_space(3))) float*)dst, 16, 0, 0);
}
__device__ __forceinline__ void wait_rem(int rem) {
    if (rem >= 3)      asm volatile("s_waitcnt vmcnt(3)" ::: "memory");
    else if (rem == 2) asm volatile("s_waitcnt vmcnt(2)" ::: "memory");
    else if (rem == 1) asm volatile("s_waitcnt vmcnt(1)" ::: "memory");
    else               asm volatile("s_waitcnt vmcnt(0)" ::: "memory");
}

// Unified gather (R8 form): flat block id -> (layer, x-or-y, channel, bl/tgt, slice).
// Each block streams its slice (csl chunks, loads issued up front) and gathers
// the samples whose index falls inside the slice.
__global__ __launch_bounds__(256) void gather(Tab tab)
{
    int f = blockIdx.x;
    int l = 0, side = 0;
    #pragma unroll
    for (int li = 0; li < MAXL; ++li) {
        if (li >= tab.nl) break;
        if (f < tab.L[li].xblk) { l = li; side = 0; goto decoded; }
        f -= tab.L[li].xblk;
        if (f < tab.L[li].yblk) { l = li; side = 1; goto decoded; }
        f -= tab.L[li].yblk;
    }
decoded:;
    const LayerP P = tab.L[l];
    int c = f % P.C; f /= P.C;
    int ytg = (tab.ysh == NT) ? NT : tab.nb;
    int gdim = side ? ytg : tab.nb;
    int grp = f % gdim;
    int h = f / gdim;

    int tid = threadIdx.x;
    int wv = tid >> 6, lane = tid & 63;
    int csl = P.csl;
    int sbase = h * csl * CHF;
    __shared__ __align__(16) float buf[4][CHF];
    __shared__ float red[4][4];

    if (side == 0) {
        int bl = grp, bg = tab.b0 + bl;
        const float* __restrict__ grow = P.g + ((size_t)bg * P.C + c) * P.n;
        const int* __restrict__ ixr = P.ix + bg * NS;
        int px[4];
        #pragma unroll
        for (int r = 0; r < 4; ++r) px[r] = ixr[tid + r * 256] - sbase;
        __builtin_amdgcn_sched_barrier(0);
        for (int d = 0; d < csl; ++d)
            gload16(grow + sbase + d * CHF + wv * 256 + lane * 4, &buf[d][wv * 256]);
        float xv[4] = {0.f, 0.f, 0.f, 0.f};
        for (int ch = 0; ch < csl; ++ch) {
            wait_rem(csl - 1 - ch);
            __builtin_amdgcn_s_barrier();
            __builtin_amdgcn_sched_barrier(0);
            #pragma unroll
            for (int r = 0; r < 4; ++r) {
                int rel = px[r] - ch * CHF;
                if ((unsigned)rel < (unsigned)CHF) xv[r] = buf[ch][rel];
            }
        }
        u16* __restrict__ xo = P.Xt + ((size_t)bl * P.C + c) * NS;
        float ax = 0.f;
        #pragma unroll
        for (int r = 0; r < 4; ++r) {
            if ((unsigned)px[r] < (unsigned)(csl * CHF)) {
                u16 hb = f2bf(xv[r]);
                xo[tid + r * 256] = hb;
                ax += bf2f(hb);
            }
        }
        for (int o = 32; o > 0; o >>= 1) ax += __shfl_down(ax, o);
        if (lane == 0) red[0][wv] = ax;
        __syncthreads();
        if (tid == 0)
            P.psx[((size_t)h * tab.nb + bl) * P.C + c] =
                red[0][0] + red[0][1] + red[0][2] + red[0][3];
    } else {
        int nk, tgt, bls[4];
        if (tab.ysh == NT) {
            nk = 4; tgt = grp;
            #pragma unroll
            for (int k = 0; k < 4; ++k) bls[k] = tgt + NT * k;
        } else {
            nk = 1; bls[0] = grp; tgt = (tab.b0 + grp) % NT;
            bls[1] = bls[2] = bls[3] = 0;
        }
        const float* __restrict__ trow = P.t + ((size_t)tgt * P.C + c) * P.n;
        int py[4][4];
        #pragma unroll
        for (int k = 0; k < 4; ++k)
            if (k < nk) {
                const int* iyr = P.iy + (tab.b0 + bls[k]) * NS;
                #pragma unroll
                for (int r = 0; r < 4; ++r) py[k][r] = iyr[tid + r * 256] - sbase;
            }
        __builtin_amdgcn_sched_barrier(0);
        for (int d = 0; d < csl; ++d)
            gload16(trow + sbase + d * CHF + wv * 256 + lane * 4, &buf[d][wv * 256]);
        float yv[4][4];
        #pragma unroll
        for (int k = 0; k < 4; ++k)
            #pragma unroll
            for (int r = 0; r < 4; ++r) yv[k][r] = 0.f;
        for (int ch = 0; ch < csl; ++ch) {
            wait_rem(csl - 1 - ch);
            __builtin_amdgcn_s_barrier();
            __builtin_amdgcn_sched_barrier(0);
            #pragma unroll
            for (int k = 0; k < 4; ++k)
                if (k < nk) {
                    #pragma unroll
                    for (int r = 0; r < 4; ++r) {
                        int rel = py[k][r] - ch * CHF;
                        if ((unsigned)rel < (unsigned)CHF) yv[k][r] = buf[ch][rel];
                    }
                }
        }
        #pragma unroll
        for (int k = 0; k < 4; ++k) {
            if (k >= nk) break;
            u16* __restrict__ yo = P.Yt + ((size_t)bls[k] * P.C + c) * NS;
            float ay = 0.f;
            #pragma unroll
            for (int r = 0; r < 4; ++r) {
                if ((unsigned)py[k][r] < (unsigned)(csl * CHF)) {
                    u16 hb = f2bf(yv[k][r]);
                    yo[tid + r * 256] = hb;
                    ay += bf2f(hb);
                }
            }
            for (int o = 32; o > 0; o >>= 1) ay += __shfl_down(ay, o);
            if (lane == 0) red[k][wv] = ay;
        }
        __syncthreads();
        if (tid < 4 && tid < nk)
            P.psy[((size_t)h * tab.nb + bls[tid]) * P.C + c] =
                red[tid][0] + red[tid][1] + red[tid][2] + red[tid][3];
    }
}

// 64x64 plain transpose (c-major -> s-major) + fused per-sample sum-of-squares.
__global__ void transpose_k(Tab tab)
{
    int x = blockIdx.x, l = 0;
    while (l < MAXL - 1 && x >= tab.L[l].C / 64) { x -= tab.L[l].C / 64; ++l; }
    const LayerP P = tab.L[l];
    int z = blockIdx.z;
    int bl = z >> 1, which = z & 1;
    const u16* __restrict__ Zt = which ? P.Yt : P.Xt;
    u16* __restrict__ Zs = which ? P.Ys : P.Xs;
    float* __restrict__ zp = which ? P.yp : P.xp;
    int C = P.C;
    int ctile = x;
    int c0 = ctile * 64, s0 = blockIdx.y * 64;
    __shared__ __align__(16) u16 T[64][72];
    int tid = threadIdx.x;
    #pragma unroll
    for (int rep = 0; rep < 2; ++rep) {
        int q = tid + rep * 256;
        int rr = q >> 3, seg = q & 7;
        *(float4*)&T[rr][seg * 8] =
            *(const float4*)&Zt[((size_t)bl * C + c0 + rr) * NS + s0 + seg * 8];
    }
    __syncthreads();
    #pragma unroll
    for (int rep = 0; rep < 2; ++rep) {
        int q = tid + rep * 256;
        int sr = q >> 3, cs = q & 7;
        __align__(16) u16 tmp[8];
        float p = 0.f;
        #pragma unroll
        for (int e = 0; e < 8; ++e) {
            u16 h = T[cs * 8 + e][sr];
            tmp[e] = h;
            float v = bf2f(h);
            p = fmaf(v, v, p);
        }
        *(float4*)&Zs[((size_t)bl * NS + s0 + sr) * C + c0 + cs * 8] = *(float4*)tmp;
        p += __shfl_xor(p, 1);
        p += __shfl_xor(p, 2);
        p += __shfl_xor(p, 4);
        if (cs == 0)
            zp[((size_t)bl * P.nchunk + ctile) * NS + s0 + sr] = p;
    }
}

// Reduce sq-partials -> reciprocal norms; init min buffers; reduce channel-sum
// slices -> sx/sy.
__global__ void colnorm_reduce(Tab tab)
{
    const LayerP P = tab.L[blockIdx.y];
    int bl = blockIdx.z;
    int nb = tab.nb;
    int s = blockIdx.x * 256 + threadIdx.x;
    float ax = 0.f, ay = 0.f;
    for (int k = 0; k < P.nchunk; ++k) {
        size_t o = ((size_t)bl * P.nchunk + k) * NS + s;
        ax += P.xp[o];
        ay += P.yp[o];
    }
    P.rxn[bl * NS + s] = rsqrtf(ax);
    P.ryn[bl * NS + s] = rsqrtf(ay);
    P.m1u[bl * NS + s] = 0xFFFFFFFFu;
    P.m2u[bl * NS + s] = 0xFFFFFFFFu;
    int cq = P.C >> 2;
    for (int c = blockIdx.x * cq + threadIdx.x; c < (blockIdx.x + 1) * cq; c += 256) {
        float sx = 0.f, sy = 0.f;
        for (int h = 0; h < P.hs; ++h) {
            sx += P.psx[((size_t)h * nb + bl) * P.C + c];
            sy += P.psy[((size_t)h * nb + bl) * P.C + c];
        }
        P.sx[bl * P.C + c] = sx;
        P.sy[bl * P.C + c] = sy;
    }
}

// 128x128 MFMA tile of cos-dist = 1 - (X.Y^T)*rx_i*ry_j; global_load_lds staging
// into unpadded [128][32] tiles (m97 pattern); fused row/col min epilogue.
__global__ __launch_bounds__(256) void cross_mfma(Tab tab)
{
    int z = blockIdx.z;
    int l = z / tab.nb, bl = z - l * tab.nb;
    const LayerP P = tab.L[l];
    int C = P.C;
    int i0 = blockIdx.x * 128, j0 = blockIdx.y * 128;
    __shared__ __align__(16) u16 As[128][32], Bs[128][32];
    int tid = threadIdx.x;
    int w = tid >> 6, lane = tid & 63;
    int wr = w >> 1, wc = w & 1;
    int q = lane >> 4, r = lane & 15;
    int lrow = lane >> 2, lseg = (lane & 3) * 8;   // staging: lane -> (row-in-16, 8-u16 seg)
    const u16* __restrict__ Xb = P.Xs + ((size_t)bl * NS + i0) * C;
    const u16* __restrict__ Yb = P.Ys + ((size_t)bl * NS + j0) * C;
    f32x4 acc[4][4];
    #pragma unroll
    for (int m = 0; m < 4; ++m)
        #pragma unroll
        for (int nn = 0; nn < 4; ++nn) acc[m][nn] = (f32x4){0.f, 0.f, 0.f, 0.f};

    for (int kk = 0; kk < C; kk += 32) {
        __syncthreads();
        #pragma unroll
        for (int it = 0; it < 2; ++it) {
            int br = (it * 4 + w) * 16;            // wave-uniform base row
            gload16(Xb + (size_t)(br + lrow) * C + kk + lseg, &As[br][0]);
            gload16(Yb + (size_t)(br + lrow) * C + kk + lseg, &Bs[br][0]);
        }
        __syncthreads();
        bf16x8 a[4], b[4];
        #pragma unroll
        for (int m = 0; m < 4; ++m)
            a[m] = *(const bf16x8*)&As[wr * 64 + m * 16 + r][q * 8];
        #pragma unroll
        for (int nn = 0; nn < 4; ++nn)
            b[nn] = *(const bf16x8*)&Bs[wc * 64 + nn * 16 + r][q * 8];
        #pragma unroll
        for (int m = 0; m < 4; ++m)
            #pragma unroll
            for (int nn = 0; nn < 4; ++nn)
                acc[m][nn] = __builtin_amdgcn_mfma_f32_16x16x32_bf16(a[m], b[nn], acc[m][nn], 0, 0, 0);
    }

    float rxl[4][4], ryl[4];
    #pragma unroll
    for (int m = 0; m < 4; ++m)
        #pragma unroll
        for (int reg = 0; reg < 4; ++reg)
            rxl[m][reg] = P.rxn[bl * NS + i0 + wr * 64 + m * 16 + q * 4 + reg];
    #pragma unroll
    for (int nn = 0; nn < 4; ++nn)
        ryl[nn] = P.ryn[bl * NS + j0 + wc * 64 + nn * 16 + r];

    float rm[4][4], cm[4];
    #pragma unroll
    for (int m = 0; m < 4; ++m)
        #pragma unroll
        for (int reg = 0; reg < 4; ++reg) rm[m][reg] = 1e30f;
    #pragma unroll
    for (int nn = 0; nn < 4; ++nn) cm[nn] = 1e30f;
    #pragma unroll
    for (int m = 0; m < 4; ++m)
        #pragma unroll
        for (int nn = 0; nn < 4; ++nn)
            #pragma unroll
            for (int reg = 0; reg < 4; ++reg) {
                float d = 1.f - acc[m][nn][reg] * rxl[m][reg] * ryl[nn];
                rm[m][reg] = fminf(rm[m][reg], d);
                cm[nn] = fminf(cm[nn], d);
            }
    #pragma unroll
    for (int m = 0; m < 4; ++m)
        #pragma unroll
        for (int reg = 0; reg < 4; ++reg) {
            float v = rm[m][reg];
            v = fminf(v, __shfl_xor(v, 1));
            v = fminf(v, __shfl_xor(v, 2));
            v = fminf(v, __shfl_xor(v, 4));
            v = fminf(v, __shfl_xor(v, 8));
            rm[m][reg] = v;
        }
    if (r == 0) {
        #pragma unroll
        for (int m = 0; m < 4; ++m)
            #pragma unroll
            for (int reg = 0; reg < 4; ++reg) {
                int i = i0 + wr * 64 + m * 16 + q * 4 + reg;
                atomicMin(&P.m2u[bl * NS + i], fenc(rm[m][reg]));
            }
    }
    #pragma unroll
    for (int nn = 0; nn < 4; ++nn) {
        float v = cm[nn];
        v = fminf(v, __shfl_xor(v, 16));
        v = fminf(v, __shfl_xor(v, 32));
        cm[nn] = v;
    }
    if (q == 0) {
        #pragma unroll
        for (int nn = 0; nn < 4; ++nn) {
            int j = j0 + wc * 64 + nn * 16 + r;
            atomicMin(&P.m1u[bl * NS + j], fenc(cm[nn]));
        }
    }
}

// Dual 128x128 MFMA tile of Sxx/Syy; global_load_lds staging into unpadded
// [128][32] tiles; upper-triangle tiles, off-diag weighted 2x.
__global__ __launch_bounds__(256) void cov_mfma(Tab tab)
{
    int x = blockIdx.x, l = 0;
    while (l < MAXL - 1 && x >= tab.L[l].ntri) { x -= tab.L[l].ntri; ++l; }
    const LayerP P = tab.L[l];
    int u = x;
    int bl = blockIdx.y;
    int C = P.C;
    int ty = 0;
    while ((ty + 1) * (ty + 2) / 2 <= u) ++ty;
    int tx = u - ty * (ty + 1) / 2;
    int c0 = ty * 128, d0 = tx * 128;
    float wgt = (tx == ty) ? 1.f : 2.f;

    __shared__ __align__(16) u16 As[128][32], Bs[128][32], Cs2[128][32], Ds[128][32];
    int tid = threadIdx.x;
    int w = tid >> 6, lane = tid & 63;
    int wr = w >> 1, wc = w & 1;
    int q = lane >> 4, r = lane & 15;
    int lrow = lane >> 2, lseg = (lane & 3) * 8;
    const u16* __restrict__ Xc = P.Xt + ((size_t)bl * C + c0) * NS;
    const u16* __restrict__ Xd = P.Xt + ((size_t)bl * C + d0) * NS;
    const u16* __restrict__ Yc = P.Yt + ((size_t)bl * C + c0) * NS;
    const u16* __restrict__ Yd = P.Yt + ((size_t)bl * C + d0) * NS;

    f32x4 accX[4][4], accY[4][4];
    #pragma unroll
    for (int m = 0; m < 4; ++m)
        #pragma unroll
        for (int nn = 0; nn < 4; ++nn) {
            accX[m][nn] = (f32x4){0.f, 0.f, 0.f, 0.f};
            accY[m][nn] = (f32x4){0.f, 0.f, 0.f, 0.f};
        }

    for (int ss = 0; ss < NS; ss += 32) {
        __syncthreads();
        #pragma unroll
        for (int it = 0; it < 2; ++it) {
            int br = (it * 4 + w) * 16;
            size_t roff = (size_t)(br + lrow) * NS + ss + lseg;
            gload16(Xc + roff, &As[br][0]);
            gload16(Xd + roff, &Bs[br][0]);
            gload16(Yc + roff, &Cs2[br][0]);
            gload16(Yd + roff, &Ds[br][0]);
        }
        __syncthreads();
        {
            bf16x8 a[4], b[4];
            #pragma unroll
            for (int m = 0; m < 4; ++m) a[m] = *(const bf16x8*)&As[wr * 64 + m * 16 + r][q * 8];
            #pragma unroll
            for (int nn = 0; nn < 4; ++nn) b[nn] = *(const bf16x8*)&Bs[wc * 64 + nn * 16 + r][q * 8];
            #pragma unroll
            for (int m = 0; m < 4; ++m)
                #pragma unroll
                for (int nn = 0; nn < 4; ++nn)
                    accX[m][nn] = __builtin_amdgcn_mfma_f32_16x16x32_bf16(a[m], b[nn], accX[m][nn], 0, 0, 0);
        }
        {
            bf16x8 a[4], b[4];
            #pragma unroll
            for (int m = 0; m < 4; ++m) a[m] = *(const bf16x8*)&Cs2[wr * 64 + m * 16 + r][q * 8];
            #pragma unroll
            for (int nn = 0; nn < 4; ++nn) b[nn] = *(const bf16x8*)&Ds[wc * 64 + nn * 16 + r][q * 8];
            #pragma unroll
            for (int m = 0; m < 4; ++m)
                #pragma unroll
                for (int nn = 0; nn < 4; ++nn)
                    accY[m][nn] = __builtin_amdgcn_mfma_f32_16x16x32_bf16(a[m], b[nn], accY[m][nn], 0, 0, 0);
        }
    }

    float scxv[4][4], scyv[4][4], sdxv[4], sdyv[4];
    #pragma unroll
    for (int m = 0; m < 4; ++m)
        #pragma unroll
        for (int reg = 0; reg < 4; ++reg) {
            int c = c0 + wr * 64 + m * 16 + q * 4 + reg;
            scxv[m][reg] = P.sx[bl * C + c];
            scyv[m][reg] = P.sy[bl * C + c];
        }
    #pragma unroll
    for (int nn = 0; nn < 4; ++nn) {
        int d = d0 + wc * 64 + nn * 16 + r;
        sdxv[nn] = P.sx[bl * C + d];
        sdyv[nn] = P.sy[bl * C + d];
    }
    const float invNS = 1.f / NS, invNSm1 = 1.f / (NS - 1);
    float tsum = 0.f;
    #pragma unroll
    for (int m = 0; m < 4; ++m)
        #pragma unroll
        for (int nn = 0; nn < 4; ++nn)
            #pragma unroll
            for (int reg = 0; reg < 4; ++reg) {
                float cx = (accX[m][nn][reg] - scxv[m][reg] * sdxv[nn] * invNS) * invNSm1;
                float cy = (accY[m][nn][reg] - scyv[m][reg] * sdyv[nn] * invNS) * invNSm1;
                tsum += fabsf(cx - cy);
            }
    tsum *= wgt;
    __shared__ float redc[4];
    for (int o = 32; o > 0; o >>= 1) tsum += __shfl_down(tsum, o);
    if (lane == 0) redc[w] = tsum;
    __syncthreads();
    if (tid == 0)
        P.cov[(size_t)bl * P.ntri + u] = redc[0] + redc[1] + redc[2] + redc[3];
}

__global__ void finalize_kernel(Tab tab)
{
    const LayerP P = tab.L[blockIdx.x];
    int bl = blockIdx.y;
    int tid = threadIdx.x;
    int C = P.C;
    float s1 = 0.f, s2 = 0.f, smu = 0.f, scov = 0.f;
    for (int s = tid; s < NS; s += 256) {
        s1 += fdec(P.m1u[bl * NS + s]);
        s2 += fdec(P.m2u[bl * NS + s]);
    }
    for (int c = tid; c < C; c += 256) smu += fabsf(P.sx[bl * C + c] - P.sy[bl * C + c]);
    for (int i = tid; i < P.ntri; i += 256) scov += P.cov[(size_t)bl * P.ntri + i];
    __shared__ float red[4][4];
    for (int o = 32; o > 0; o >>= 1) {
        s1 += __shfl_down(s1, o);
        s2 += __shfl_down(s2, o);
        smu += __shfl_down(smu, o);
        scov += __shfl_down(scov, o);
    }
    int wid = tid >> 6, lane = tid & 63;
    if (lane == 0) { red[0][wid] = s1; red[1][wid] = s2; red[2][wid] = smu; red[3][wid] = scov; }
    __syncthreads();
    if (tid == 0) {
        s1 = red[0][0] + red[0][1] + red[0][2] + red[0][3];
        s2 = red[1][0] + red[1][1] + red[1][2] + red[1][3];
        smu = red[2][0] + red[2][1] + red[2][2] + red[2][3];
        scov = red[3][0] + red[3][1] + red[3][2] + red[3][3];
        float m1m = s1 * (1.f / NS), m2m = s2 * (1.f / NS);
        float mu_diff = smu * (1.f / NS) * (1.f / (float)C);
        float cov_diff = scov / ((float)C * (float)C);
        tab.losspart[(tab.b0 + bl) * 3 + P.lid] = fmaxf(m1m, m2m) + mu_diff + cov_diff;
    }
}

__global__ void out_kernel(const float* __restrict__ lp, float* __restrict__ out)
{
    int t = threadIdx.x;
    if (t < NT) {
        float s = 0.f;
        for (int k = 0; k < BSZ; ++k)
            for (int l = 0; l < 3; ++l)
                s += lp[(k * NT + t) * 3 + l];
        out[t] = s * (1.f / BSZ);
    }
}

static inline size_t alignup(size_t v) { return (v + 255) & ~(size_t)255; }

static void geo(int n, int& hs, int& csl) {
    int nch = n >> 10;
    if (nch < 1) nch = 1;
    hs = (nch >= 4) ? nch / 4 : 1;
    csl = nch / hs;
}

static size_t layer_bytes(int C, int n, int nb) {
    int nchunk = C / 64;
    int tc = C / 128, ntri = tc * (tc + 1) / 2;
    int hs, csl; geo(n, hs, csl);
    size_t szZ = alignup((size_t)NS * C * 2);
    size_t szP = alignup((size_t)nchunk * NS * 4);
    size_t szPS = alignup((size_t)hs * nb * C * 4);
    return (size_t)nb * (4 * szZ + 2 * szP + 4 * alignup(NS * 4)
                         + 2 * alignup(C * 4) + alignup(ntri * 4))
           + 2 * szPS;
}

static char* fill_layer(LayerP& P, char* p, int C, int n, int nb, int ysh, int lid,
                        const float* g, const float* t, const int* ix, const int* iy) {
    P.g = g; P.t = t; P.ix = ix; P.iy = iy;
    P.C = C; P.n = n; P.lid = lid;
    P.nchunk = C / 64;
    int tc = C / 128;
    P.ntri = tc * (tc + 1) / 2;
    geo(n, P.hs, P.csl);
    P.xblk = C * P.hs * nb;
    P.yblk = C * P.hs * ((ysh == NT) ? NT : nb);
    size_t szZ = alignup((size_t)NS * C * 2);
    size_t szP = alignup((size_t)P.nchunk * NS * 4);
    size_t szPS = alignup((size_t)P.hs * nb * C * 4);
    P.Xt = (u16*)p;  p += nb * szZ;
    P.Yt = (u16*)p;  p += nb * szZ;
    P.Xs = (u16*)p;  p += nb * szZ;
    P.Ys = (u16*)p;  p += nb * szZ;
    P.xp = (float*)p; p += nb * szP;
    P.yp = (float*)p; p += nb * szP;
    P.psx = (float*)p; p += szPS;
    P.psy = (float*)p; p += szPS;
    P.rxn = (float*)p; p += nb * alignup(NS * 4);
    P.ryn = (float*)p; p += nb * alignup(NS * 4);
    P.m1u = (unsigned*)p; p += nb * alignup(NS * 4);
    P.m2u = (unsigned*)p; p += nb * alignup(NS * 4);
    P.sx = (float*)p; p += nb * alignup(C * 4);
    P.sy = (float*)p; p += nb * alignup(C * 4);
    P.cov = (float*)p; p += nb * alignup(P.ntri * 4);
    return p;
}

static void launch_group(const Tab& tab, hipStream_t stream) {
    int sumC64 = 0, sumNtri = 0, flatN = 0;
    for (int l = 0; l < tab.nl; ++l) {
        sumC64 += tab.L[l].C / 64;
        sumNtri += tab.L[l].ntri;
        flatN += tab.L[l].xblk + tab.L[l].yblk;
    }
    int nb = tab.nb;
    gather<<<flatN, 256, 0, stream>>>(tab);
    transpose_k<<<dim3(sumC64, NS / 64, nb * 2), 256, 0, stream>>>(tab);
    colnorm_reduce<<<dim3(NS / 256, tab.nl, nb), 256, 0, stream>>>(tab);
    cross_mfma<<<dim3(NS / 128, NS / 128, tab.nl * nb), 256, 0, stream>>>(tab);
    cov_mfma<<<dim3(sumNtri, nb), 256, 0, stream>>>(tab);
    finalize_kernel<<<dim3(tab.nl, nb), 256, 0, stream>>>(tab);
}

extern "C" void kernel_launch(void* const* d_in, const int* in_sizes, int n_in,
                              void* d_out, int out_size, void* d_ws, size_t ws_size,
                              hipStream_t stream)
{
    const float* tp[3] = {(const float*)d_in[0], (const float*)d_in[4], (const float*)d_in[8]};
    const float* gp[3] = {(const float*)d_in[1], (const float*)d_in[5], (const float*)d_in[9]};
    const int* ixp[3]  = {(const int*)d_in[2], (const int*)d_in[6], (const int*)d_in[10]};
    const int* iyp[3]  = {(const int*)d_in[3], (const int*)d_in[7], (const int*)d_in[11]};
    const int Cs[3] = {128, 256, 512};
    const int Sp[3] = {128, 64, 32};

    float* out = (float*)d_out;
    char* ws = (char*)d_ws;
    float* losspart = (float*)ws;           // BB*3 floats
    size_t base = alignup(BB * 3 * 4);
    size_t avail = (ws_size > base) ? ws_size - base : 0;

    size_t need_all = 0;
    for (int l = 0; l < 3; ++l) need_all += layer_bytes(Cs[l], Sp[l] * Sp[l], BB);

    if (avail >= need_all) {
        Tab tab;
        tab.nl = 3; tab.nb = BB; tab.b0 = 0; tab.ysh = NT; tab.losspart = losspart;
        char* p = ws + base;
        for (int l = 0; l < 3; ++l)
            p = fill_layer(tab.L[l], p, Cs[l], Sp[l] * Sp[l], BB, NT, l,
                           gp[l], tp[l], ixp[l], iyp[l]);
        launch_group(tab, stream);
    } else {
        for (int l = 0; l < 3; ++l) {
            size_t per_b = layer_bytes(Cs[l], Sp[l] * Sp[l], 1);
            int G = (int)(avail / per_b);
            if (G > BB) G = BB;
            if (G < 1) G = 1;
            for (int b0 = 0; b0 < BB; b0 += G) {
                int nb = (BB - b0 < G) ? (BB - b0) : G;
                Tab tab;
                tab.nl = 1; tab.nb = nb; tab.b0 = b0; tab.ysh = 1; tab.losspart = losspart;
                fill_layer(tab.L[0], ws + base, Cs[l], Sp[l] * Sp[l], nb, 1, l,
                           gp[l], tp[l], ixp[l], iyp[l]);
                launch_group(tab, stream);
            }
        }
    }
    out_kernel<<<1, 64, 0, stream>>>(losspart, out);
}